// Round 1
// baseline (145.172 us; speedup 1.0000x reference)
//
#include <hip/hip_runtime.h>

#define CC  256
#define HW  4096
#define HH  64
#define WW  64
#define RED 64
#define K2  49
#define NG  16
#define GCH 16

// Block: 512 threads = 8 waves. lane = x (0..63), wave wv = 0..7 output split.
// Grid: 256 = b(2) * y(64) * gsel(2).  gsel splits the 16 groups 8/8.
__global__ __launch_bounds__(512, 1) void crossinv_kernel(
    const float* __restrict__ feat,
    const float* __restrict__ guide,
    const float* __restrict__ w1,
    const float* __restrict__ gamma,
    const float* __restrict__ beta,
    const float* __restrict__ mean,
    const float* __restrict__ var,
    const float* __restrict__ w2,
    const float* __restrict__ b2,
    float* __restrict__ out)
{
    __shared__ float st[RED][WW];   // t[r][x]      16 KB
    __shared__ float wg[K2][WW];    // weight[k][x] 12.25 KB

    const int bid  = blockIdx.x;
    const int bb   = bid >> 7;         // batch
    const int y    = (bid >> 1) & 63;  // row
    const int gsel = bid & 1;          // group half

    const int lane = threadIdx.x & 63;
    // wave index; readfirstlane forces SGPR -> weight loads become s_loads
    const int wv   = __builtin_amdgcn_readfirstlane(threadIdx.x >> 6);

    // ---------- Phase A: t[o][x] = relu(BN(w1 . guide(:,y,x))) ----------
    const float* gptr = guide + (size_t)bb * CC * HW + (size_t)y * WW + lane;
    float acc[8];
    #pragma unroll
    for (int j = 0; j < 8; ++j) acc[j] = 0.f;

    for (int c0 = 0; c0 < CC; c0 += 4) {
        const float gv0 = gptr[(c0 + 0) * HW];
        const float gv1 = gptr[(c0 + 1) * HW];
        const float gv2 = gptr[(c0 + 2) * HW];
        const float gv3 = gptr[(c0 + 3) * HW];
        #pragma unroll
        for (int j = 0; j < 8; ++j) {
            const int o = wv + 8 * j;                      // wave-uniform
            const float4 wr = *reinterpret_cast<const float4*>(w1 + o * CC + c0);
            acc[j] = fmaf(wr.x, gv0, acc[j]);
            acc[j] = fmaf(wr.y, gv1, acc[j]);
            acc[j] = fmaf(wr.z, gv2, acc[j]);
            acc[j] = fmaf(wr.w, gv3, acc[j]);
        }
    }
    #pragma unroll
    for (int j = 0; j < 8; ++j) {
        const int o = wv + 8 * j;
        const float sc = gamma[o] * rsqrtf(var[o] + 1e-5f);
        const float sh = beta[o] - mean[o] * sc;
        const float v  = fmaf(acc[j], sc, sh);
        st[o][lane] = v > 0.f ? v : 0.f;
    }
    __syncthreads();

    // ---------- per group: Phase B (gen weights) then Phase C (involution) ----------
    for (int gi = 0; gi < 8; ++gi) {
        const int g     = gsel * 8 + gi;
        const int obase = g * K2;

        // Phase B: wg[o2][x] = b2[o2] + w2[o2,:] . t[:,x]
        float accw[7];
        #pragma unroll
        for (int j = 0; j < 7; ++j) {
            const int o2 = wv + 8 * j;
            accw[j] = (o2 < K2) ? b2[obase + o2] : 0.f;
        }
        for (int r0 = 0; r0 < RED; r0 += 4) {
            const float t0 = st[r0 + 0][lane];
            const float t1 = st[r0 + 1][lane];
            const float t2 = st[r0 + 2][lane];
            const float t3 = st[r0 + 3][lane];
            #pragma unroll
            for (int j = 0; j < 7; ++j) {
                const int o2 = wv + 8 * j;                 // wave-uniform
                if (o2 < K2) {
                    const float4 wr = *reinterpret_cast<const float4*>(
                        w2 + (size_t)(obase + o2) * RED + r0);
                    accw[j] = fmaf(wr.x, t0, accw[j]);
                    accw[j] = fmaf(wr.y, t1, accw[j]);
                    accw[j] = fmaf(wr.z, t2, accw[j]);
                    accw[j] = fmaf(wr.w, t3, accw[j]);
                }
            }
        }
        #pragma unroll
        for (int j = 0; j < 7; ++j) {
            const int o2 = wv + 8 * j;
            if (o2 < K2) wg[o2][lane] = accw[j];
        }
        __syncthreads();

        // Phase C: out[c] = feat[c] + sum_k wg[k] * feat[c, y+dy, x+dx]
        #pragma unroll
        for (int cc2 = 0; cc2 < 2; ++cc2) {
            const int cc = wv * 2 + cc2;
            const int c  = g * GCH + cc;
            const float* fb = feat + ((size_t)bb * CC + c) * HW;
            float sum = fb[y * WW + lane];                 // residual
            #pragma unroll
            for (int i = 0; i < 7; ++i) {
                const int yy = y + i - 3;
                if (yy < 0 || yy >= HH) continue;          // uniform branch
                const float* frow = fb + yy * WW;
                #pragma unroll
                for (int jx = 0; jx < 7; ++jx) {
                    const int xx = lane + jx - 3;
                    const float fv = (xx >= 0 && xx < WW) ? frow[xx] : 0.f;
                    sum = fmaf(wg[i * 7 + jx][lane], fv, sum);
                }
            }
            out[((size_t)bb * CC + c) * HW + (size_t)y * WW + lane] = sum;
        }
        __syncthreads();
    }
}

extern "C" void kernel_launch(void* const* d_in, const int* in_sizes, int n_in,
                              void* d_out, int out_size, void* d_ws, size_t ws_size,
                              hipStream_t stream) {
    const float* feat  = (const float*)d_in[0];
    const float* guide = (const float*)d_in[1];
    const float* w1    = (const float*)d_in[2];
    const float* gamma = (const float*)d_in[3];
    const float* beta  = (const float*)d_in[4];
    const float* mean  = (const float*)d_in[5];
    const float* var   = (const float*)d_in[6];
    const float* w2    = (const float*)d_in[7];
    const float* b2    = (const float*)d_in[8];
    float* out = (float*)d_out;

    hipLaunchKernelGGL(crossinv_kernel, dim3(256), dim3(512), 0, stream,
                       feat, guide, w1, gamma, beta, mean, var, w2, b2, out);
}

// Round 2
// 72.561 us; speedup vs baseline: 2.0007x; 2.0007x over previous
//
#include <hip/hip_runtime.h>

#define CC  256
#define HW  4096
#define HH  64
#define WW  64
#define RED 64
#define K2  49
#define NG  16
#define GCH 16

// ================= Kernel 1: t[b,r,y,x] = relu(BN(w1 . guide)) =================
// grid: (b, y, oh) = 2*64*2 = 256 blocks, 512 thr (8 waves).
// wave wv computes 4 outputs o = oh*32 + wv*4 + j.
__global__ __launch_bounds__(512, 1) void k1_t_kernel(
    const float* __restrict__ guide,
    const float* __restrict__ w1,
    const float* __restrict__ gamma,
    const float* __restrict__ beta,
    const float* __restrict__ mean,
    const float* __restrict__ var,
    float* __restrict__ t_out)
{
    const int bid = blockIdx.x;
    const int bb  = bid >> 7;
    const int y   = (bid >> 1) & 63;
    const int oh  = bid & 1;
    const int lane = threadIdx.x & 63;
    const int wv   = __builtin_amdgcn_readfirstlane(threadIdx.x >> 6);
    const int ob   = oh * 32 + wv * 4;

    const float* gptr = guide + (size_t)bb * CC * HW + (size_t)y * WW + lane;
    float acc[4] = {0.f, 0.f, 0.f, 0.f};

    for (int c0 = 0; c0 < CC; c0 += 4) {
        const float g0 = gptr[(c0 + 0) * HW];
        const float g1 = gptr[(c0 + 1) * HW];
        const float g2 = gptr[(c0 + 2) * HW];
        const float g3 = gptr[(c0 + 3) * HW];
        #pragma unroll
        for (int j = 0; j < 4; ++j) {
            const float4 wr = *reinterpret_cast<const float4*>(w1 + (ob + j) * CC + c0);
            acc[j] = fmaf(wr.x, g0, acc[j]);
            acc[j] = fmaf(wr.y, g1, acc[j]);
            acc[j] = fmaf(wr.z, g2, acc[j]);
            acc[j] = fmaf(wr.w, g3, acc[j]);
        }
    }
    #pragma unroll
    for (int j = 0; j < 4; ++j) {
        const int o = ob + j;
        const float sc = gamma[o] * rsqrtf(var[o] + 1e-5f);
        const float sh = beta[o] - mean[o] * sc;
        const float v  = fmaf(acc[j], sc, sh);
        t_out[(size_t)(bb * RED + o) * HW + (size_t)y * WW + lane] = v > 0.f ? v : 0.f;
    }
}

// ================= Kernel 2: weights (phase B) + involution (phase C) =================
// grid: (b, y, g) = 2*64*16 = 2048 blocks, 256 thr (4 waves).
__global__ __launch_bounds__(256, 1) void k2_inv_kernel(
    const float* __restrict__ feat,
    const float* __restrict__ t_in,
    const float* __restrict__ w2,
    const float* __restrict__ b2,
    float* __restrict__ out)
{
    __shared__ float st[RED][WW];   // 16 KB
    __shared__ float wg[K2][WW];    // 12.25 KB

    const int bid = blockIdx.x;
    const int bb  = bid >> 10;
    const int y   = (bid >> 4) & 63;
    const int g   = bid & 15;
    const int tid  = threadIdx.x;
    const int lane = tid & 63;
    const int wv   = __builtin_amdgcn_readfirstlane(tid >> 6);

    // ---- load t tile (64 rows x 64 px) from ws, float4-coalesced ----
    {
        const float* tb = t_in + (size_t)bb * RED * HW + (size_t)y * WW;
        #pragma unroll
        for (int it = 0; it < 4; ++it) {
            const int idx = it * 256 + tid;   // float4 index 0..1023
            const int r   = idx >> 4;         // 16 float4 per row
            const int q   = idx & 15;
            const float4 v = *reinterpret_cast<const float4*>(tb + (size_t)r * HW + q * 4);
            *reinterpret_cast<float4*>(&st[r][q * 4]) = v;
        }
    }
    __syncthreads();

    // ---- Phase B: wg[o2][x] = b2 + w2[o2,:] . t[:,x]; wave rows o2 = wv + 4*j ----
    const int obase = g * K2;
    float accw[13];
    #pragma unroll
    for (int j = 0; j < 13; ++j) {
        const int o2 = wv + 4 * j;
        accw[j] = (o2 < K2) ? b2[obase + o2] : 0.f;
    }
    for (int r0 = 0; r0 < RED; r0 += 4) {
        const float t0 = st[r0 + 0][lane];
        const float t1 = st[r0 + 1][lane];
        const float t2 = st[r0 + 2][lane];
        const float t3 = st[r0 + 3][lane];
        #pragma unroll
        for (int j = 0; j < 13; ++j) {
            const int o2 = wv + 4 * j;                      // wave-uniform
            if (o2 < K2) {
                const float4 wr = *reinterpret_cast<const float4*>(
                    w2 + (size_t)(obase + o2) * RED + r0);
                accw[j] = fmaf(wr.x, t0, accw[j]);
                accw[j] = fmaf(wr.y, t1, accw[j]);
                accw[j] = fmaf(wr.z, t2, accw[j]);
                accw[j] = fmaf(wr.w, t3, accw[j]);
            }
        }
    }
    #pragma unroll
    for (int j = 0; j < 13; ++j) {
        const int o2 = wv + 4 * j;
        if (o2 < K2) wg[o2][lane] = accw[j];
    }
    __syncthreads();

    // ---- Phase C: involution + residual; wave handles channels wv + 4*i2 ----
    float wk[K2];
    #pragma unroll
    for (int k = 0; k < K2; ++k) wk[k] = wg[k][lane];

    #pragma unroll
    for (int i2 = 0; i2 < 4; ++i2) {
        const int c = g * GCH + wv + 4 * i2;
        const float* fb = feat + ((size_t)bb * CC + c) * HW;
        float sum = fb[(size_t)y * WW + lane];             // residual
        #pragma unroll
        for (int i = 0; i < 7; ++i) {
            const int yy = y + i - 3;
            if (yy < 0 || yy >= HH) continue;              // uniform branch
            const float* frow = fb + (size_t)yy * WW;
            #pragma unroll
            for (int jx = 0; jx < 7; ++jx) {
                const int xx = lane + jx - 3;
                const float fv = (xx >= 0 && xx < WW) ? frow[xx] : 0.f;
                sum = fmaf(wk[i * 7 + jx], fv, sum);
            }
        }
        out[((size_t)bb * CC + c) * HW + (size_t)y * WW + lane] = sum;
    }
}

// ================= Fallback: round-1 fused kernel (used only if ws too small) =================
__global__ __launch_bounds__(512, 1) void crossinv_fused_kernel(
    const float* __restrict__ feat, const float* __restrict__ guide,
    const float* __restrict__ w1, const float* __restrict__ gamma,
    const float* __restrict__ beta, const float* __restrict__ mean,
    const float* __restrict__ var, const float* __restrict__ w2,
    const float* __restrict__ b2, float* __restrict__ out)
{
    __shared__ float st[RED][WW];
    __shared__ float wg[K2][WW];
    const int bid  = blockIdx.x;
    const int bb   = bid >> 7;
    const int y    = (bid >> 1) & 63;
    const int gsel = bid & 1;
    const int lane = threadIdx.x & 63;
    const int wv   = __builtin_amdgcn_readfirstlane(threadIdx.x >> 6);

    const float* gptr = guide + (size_t)bb * CC * HW + (size_t)y * WW + lane;
    float acc[8];
    #pragma unroll
    for (int j = 0; j < 8; ++j) acc[j] = 0.f;
    for (int c0 = 0; c0 < CC; c0 += 4) {
        const float gv0 = gptr[(c0 + 0) * HW];
        const float gv1 = gptr[(c0 + 1) * HW];
        const float gv2 = gptr[(c0 + 2) * HW];
        const float gv3 = gptr[(c0 + 3) * HW];
        #pragma unroll
        for (int j = 0; j < 8; ++j) {
            const int o = wv + 8 * j;
            const float4 wr = *reinterpret_cast<const float4*>(w1 + o * CC + c0);
            acc[j] = fmaf(wr.x, gv0, acc[j]);
            acc[j] = fmaf(wr.y, gv1, acc[j]);
            acc[j] = fmaf(wr.z, gv2, acc[j]);
            acc[j] = fmaf(wr.w, gv3, acc[j]);
        }
    }
    #pragma unroll
    for (int j = 0; j < 8; ++j) {
        const int o = wv + 8 * j;
        const float sc = gamma[o] * rsqrtf(var[o] + 1e-5f);
        const float sh = beta[o] - mean[o] * sc;
        const float v  = fmaf(acc[j], sc, sh);
        st[o][lane] = v > 0.f ? v : 0.f;
    }
    __syncthreads();
    for (int gi = 0; gi < 8; ++gi) {
        const int gg    = gsel * 8 + gi;
        const int obase = gg * K2;
        float accw[7];
        #pragma unroll
        for (int j = 0; j < 7; ++j) {
            const int o2 = wv + 8 * j;
            accw[j] = (o2 < K2) ? b2[obase + o2] : 0.f;
        }
        for (int r0 = 0; r0 < RED; r0 += 4) {
            const float t0 = st[r0 + 0][lane];
            const float t1 = st[r0 + 1][lane];
            const float t2 = st[r0 + 2][lane];
            const float t3 = st[r0 + 3][lane];
            #pragma unroll
            for (int j = 0; j < 7; ++j) {
                const int o2 = wv + 8 * j;
                if (o2 < K2) {
                    const float4 wr = *reinterpret_cast<const float4*>(
                        w2 + (size_t)(obase + o2) * RED + r0);
                    accw[j] = fmaf(wr.x, t0, accw[j]);
                    accw[j] = fmaf(wr.y, t1, accw[j]);
                    accw[j] = fmaf(wr.z, t2, accw[j]);
                    accw[j] = fmaf(wr.w, t3, accw[j]);
                }
            }
        }
        #pragma unroll
        for (int j = 0; j < 7; ++j) {
            const int o2 = wv + 8 * j;
            if (o2 < K2) wg[o2][lane] = accw[j];
        }
        __syncthreads();
        #pragma unroll
        for (int cc2 = 0; cc2 < 2; ++cc2) {
            const int cc = wv * 2 + cc2;
            const int c  = gg * GCH + cc;
            const float* fb = feat + ((size_t)bb * CC + c) * HW;
            float sum = fb[y * WW + lane];
            #pragma unroll
            for (int i = 0; i < 7; ++i) {
                const int yy = y + i - 3;
                if (yy < 0 || yy >= HH) continue;
                const float* frow = fb + yy * WW;
                #pragma unroll
                for (int jx = 0; jx < 7; ++jx) {
                    const int xx = lane + jx - 3;
                    const float fv = (xx >= 0 && xx < WW) ? frow[xx] : 0.f;
                    sum = fmaf(wg[i * 7 + jx][lane], fv, sum);
                }
            }
            out[((size_t)bb * CC + c) * HW + (size_t)y * WW + lane] = sum;
        }
        __syncthreads();
    }
}

extern "C" void kernel_launch(void* const* d_in, const int* in_sizes, int n_in,
                              void* d_out, int out_size, void* d_ws, size_t ws_size,
                              hipStream_t stream) {
    const float* feat  = (const float*)d_in[0];
    const float* guide = (const float*)d_in[1];
    const float* w1    = (const float*)d_in[2];
    const float* gamma = (const float*)d_in[3];
    const float* beta  = (const float*)d_in[4];
    const float* mean  = (const float*)d_in[5];
    const float* var   = (const float*)d_in[6];
    const float* w2    = (const float*)d_in[7];
    const float* b2    = (const float*)d_in[8];
    float* out = (float*)d_out;

    const size_t t_bytes = (size_t)2 * RED * HW * sizeof(float);  // 2 MB
    if (ws_size >= t_bytes) {
        float* t_ws = (float*)d_ws;
        hipLaunchKernelGGL(k1_t_kernel, dim3(256), dim3(512), 0, stream,
                           guide, w1, gamma, beta, mean, var, t_ws);
        hipLaunchKernelGGL(k2_inv_kernel, dim3(2048), dim3(256), 0, stream,
                           feat, t_ws, w2, b2, out);
    } else {
        hipLaunchKernelGGL(crossinv_fused_kernel, dim3(256), dim3(512), 0, stream,
                           feat, guide, w1, gamma, beta, mean, var, w2, b2, out);
    }
}

// Round 3
// 53.339 us; speedup vs baseline: 2.7217x; 1.3604x over previous
//
#include <hip/hip_runtime.h>

#define CC  256
#define HW  4096
#define HH  64
#define WW  64
#define RED 64
#define K2  49
#define NG  16
#define GCH 16

// ================= Kernel 1: t[b,r,y,x] = relu(BN(w1 . guide)) =================
// grid: (b, y, oq) = 2*64*4 = 512 blocks, 256 thr.
// thread = (o = oq*16 + tid>>4, xq = tid&15) computes 4 adjacent x.
__global__ __launch_bounds__(256, 4) void k1_t_kernel(
    const float* __restrict__ guide,
    const float* __restrict__ w1,
    const float* __restrict__ gamma,
    const float* __restrict__ beta,
    const float* __restrict__ mean,
    const float* __restrict__ var,
    float* __restrict__ t_out)
{
    const int bid = blockIdx.x;
    const int bb  = bid >> 8;
    const int y   = (bid >> 2) & 63;
    const int oq  = bid & 3;
    const int tid = threadIdx.x;
    const int o   = oq * 16 + (tid >> 4);
    const int xq  = tid & 15;
    const int x0  = xq * 4;

    const float* gb   = guide + (size_t)bb * CC * HW + (size_t)y * WW + x0;
    const float* wrow = w1 + (size_t)o * CC;

    float a0 = 0.f, a1 = 0.f, a2 = 0.f, a3 = 0.f;

    #pragma unroll 4
    for (int c0 = 0; c0 < CC; c0 += 4) {
        const float4 w4 = *reinterpret_cast<const float4*>(wrow + c0);
        const float4 g0 = *reinterpret_cast<const float4*>(gb + (size_t)(c0 + 0) * HW);
        const float4 g1 = *reinterpret_cast<const float4*>(gb + (size_t)(c0 + 1) * HW);
        const float4 g2 = *reinterpret_cast<const float4*>(gb + (size_t)(c0 + 2) * HW);
        const float4 g3 = *reinterpret_cast<const float4*>(gb + (size_t)(c0 + 3) * HW);
        a0 = fmaf(w4.x, g0.x, a0); a1 = fmaf(w4.x, g0.y, a1);
        a2 = fmaf(w4.x, g0.z, a2); a3 = fmaf(w4.x, g0.w, a3);
        a0 = fmaf(w4.y, g1.x, a0); a1 = fmaf(w4.y, g1.y, a1);
        a2 = fmaf(w4.y, g1.z, a2); a3 = fmaf(w4.y, g1.w, a3);
        a0 = fmaf(w4.z, g2.x, a0); a1 = fmaf(w4.z, g2.y, a1);
        a2 = fmaf(w4.z, g2.z, a2); a3 = fmaf(w4.z, g2.w, a3);
        a0 = fmaf(w4.w, g3.x, a0); a1 = fmaf(w4.w, g3.y, a1);
        a2 = fmaf(w4.w, g3.z, a2); a3 = fmaf(w4.w, g3.w, a3);
    }

    const float sc = gamma[o] * rsqrtf(var[o] + 1e-5f);
    const float sh = beta[o] - mean[o] * sc;
    float4 r;
    r.x = fmaf(a0, sc, sh); r.y = fmaf(a1, sc, sh);
    r.z = fmaf(a2, sc, sh); r.w = fmaf(a3, sc, sh);
    r.x = r.x > 0.f ? r.x : 0.f;
    r.y = r.y > 0.f ? r.y : 0.f;
    r.z = r.z > 0.f ? r.z : 0.f;
    r.w = r.w > 0.f ? r.w : 0.f;
    *reinterpret_cast<float4*>(t_out + (size_t)(bb * RED + o) * HW + (size_t)y * WW + x0) = r;
}

// ================= Kernel 2: weights (phase B) + involution (phase C) =================
// grid: (b, y, g) = 2*64*16 = 2048 blocks, 256 thr (4 waves).
__global__ __launch_bounds__(256, 4) void k2_inv_kernel(
    const float* __restrict__ feat,
    const float* __restrict__ t_in,
    const float* __restrict__ w2,
    const float* __restrict__ b2,
    float* __restrict__ out)
{
    __shared__ float wg[K2][WW];    // 12.25 KB

    const int bid = blockIdx.x;
    const int bb  = bid >> 10;
    const int y   = (bid >> 4) & 63;
    const int g   = bid & 15;
    const int tid  = threadIdx.x;
    const int lane = tid & 63;
    const int wv   = __builtin_amdgcn_readfirstlane(tid >> 6);
    const int obase = g * K2;

    // ---- Phase B: t column straight into 64 VGPRs (coalesced, L2-hot) ----
    float tv[RED];
    {
        const float* tb = t_in + (size_t)bb * RED * HW + (size_t)y * WW + lane;
        #pragma unroll
        for (int r = 0; r < RED; ++r) tv[r] = tb[(size_t)r * HW];
    }

    float acc[13];
    #pragma unroll
    for (int j = 0; j < 13; ++j) {
        const int o2 = wv + 4 * j;
        acc[j] = (o2 < K2) ? b2[obase + o2] : 0.f;
    }
    #pragma unroll
    for (int j = 0; j < 13; ++j) {
        const int o2 = wv + 4 * j;                 // wave-uniform -> s_load
        if (o2 < K2) {
            const float* wrow = w2 + (size_t)(obase + o2) * RED;
            #pragma unroll
            for (int r = 0; r < RED; ++r)
                acc[j] = fmaf(wrow[r], tv[r], acc[j]);
        }
    }
    #pragma unroll
    for (int j = 0; j < 13; ++j) {
        const int o2 = wv + 4 * j;
        if (o2 < K2) wg[o2][lane] = acc[j];
    }
    __syncthreads();

    // ---- Phase C: thread = (channel cl, x-quad xq); 4 adjacent px per thread ----
    const int cl = tid >> 4;           // 0..15
    const int xq = tid & 15;           // 0..15
    const int x0 = xq * 4;
    const int c  = g * GCH + cl;
    const float* fb = feat + ((size_t)bb * CC + c) * HW;

    const float4 res = *reinterpret_cast<const float4*>(fb + (size_t)y * WW + x0);
    float s0 = res.x, s1 = res.y, s2 = res.z, s3 = res.w;   // residual

    #pragma unroll
    for (int i = 0; i < 7; ++i) {
        const int yy = y + i - 3;
        if (yy < 0 || yy >= HH) continue;          // block-uniform branch
        const float* frow = fb + (size_t)yy * WW;

        // 12-float register window: f[x0-4 .. x0+7]
        float4 Lw = make_float4(0.f, 0.f, 0.f, 0.f);
        float4 Rw = make_float4(0.f, 0.f, 0.f, 0.f);
        const float4 Mw = *reinterpret_cast<const float4*>(frow + x0);
        if (xq > 0)  Lw = *reinterpret_cast<const float4*>(frow + x0 - 4);
        if (xq < 15) Rw = *reinterpret_cast<const float4*>(frow + x0 + 4);
        const float buf[12] = {Lw.x, Lw.y, Lw.z, Lw.w,
                               Mw.x, Mw.y, Mw.z, Mw.w,
                               Rw.x, Rw.y, Rw.z, Rw.w};

        #pragma unroll
        for (int jx = 0; jx < 7; ++jx) {
            const float4 w4 = *reinterpret_cast<const float4*>(&wg[i * 7 + jx][x0]);
            s0 = fmaf(w4.x, buf[jx + 1], s0);
            s1 = fmaf(w4.y, buf[jx + 2], s1);
            s2 = fmaf(w4.z, buf[jx + 3], s2);
            s3 = fmaf(w4.w, buf[jx + 4], s3);
        }
    }

    float4 o4; o4.x = s0; o4.y = s1; o4.z = s2; o4.w = s3;
    *reinterpret_cast<float4*>(out + ((size_t)bb * CC + c) * HW + (size_t)y * WW + x0) = o4;
}

// ================= Fallback: fused single kernel (used only if ws too small) =================
__global__ __launch_bounds__(512, 1) void crossinv_fused_kernel(
    const float* __restrict__ feat, const float* __restrict__ guide,
    const float* __restrict__ w1, const float* __restrict__ gamma,
    const float* __restrict__ beta, const float* __restrict__ mean,
    const float* __restrict__ var, const float* __restrict__ w2,
    const float* __restrict__ b2, float* __restrict__ out)
{
    __shared__ float st[RED][WW];
    __shared__ float wg[K2][WW];
    const int bid  = blockIdx.x;
    const int bb   = bid >> 7;
    const int y    = (bid >> 1) & 63;
    const int gsel = bid & 1;
    const int lane = threadIdx.x & 63;
    const int wv   = __builtin_amdgcn_readfirstlane(threadIdx.x >> 6);

    const float* gptr = guide + (size_t)bb * CC * HW + (size_t)y * WW + lane;
    float acc[8];
    #pragma unroll
    for (int j = 0; j < 8; ++j) acc[j] = 0.f;
    for (int c0 = 0; c0 < CC; c0 += 4) {
        const float gv0 = gptr[(c0 + 0) * HW];
        const float gv1 = gptr[(c0 + 1) * HW];
        const float gv2 = gptr[(c0 + 2) * HW];
        const float gv3 = gptr[(c0 + 3) * HW];
        #pragma unroll
        for (int j = 0; j < 8; ++j) {
            const int o = wv + 8 * j;
            const float4 wr = *reinterpret_cast<const float4*>(w1 + o * CC + c0);
            acc[j] = fmaf(wr.x, gv0, acc[j]);
            acc[j] = fmaf(wr.y, gv1, acc[j]);
            acc[j] = fmaf(wr.z, gv2, acc[j]);
            acc[j] = fmaf(wr.w, gv3, acc[j]);
        }
    }
    #pragma unroll
    for (int j = 0; j < 8; ++j) {
        const int o = wv + 8 * j;
        const float sc = gamma[o] * rsqrtf(var[o] + 1e-5f);
        const float sh = beta[o] - mean[o] * sc;
        const float v  = fmaf(acc[j], sc, sh);
        st[o][lane] = v > 0.f ? v : 0.f;
    }
    __syncthreads();
    for (int gi = 0; gi < 8; ++gi) {
        const int gg    = gsel * 8 + gi;
        const int obase = gg * K2;
        float accw[7];
        #pragma unroll
        for (int j = 0; j < 7; ++j) {
            const int o2 = wv + 8 * j;
            accw[j] = (o2 < K2) ? b2[obase + o2] : 0.f;
        }
        for (int r0 = 0; r0 < RED; r0 += 4) {
            const float t0 = st[r0 + 0][lane];
            const float t1 = st[r0 + 1][lane];
            const float t2 = st[r0 + 2][lane];
            const float t3 = st[r0 + 3][lane];
            #pragma unroll
            for (int j = 0; j < 7; ++j) {
                const int o2 = wv + 8 * j;
                if (o2 < K2) {
                    const float4 wr = *reinterpret_cast<const float4*>(
                        w2 + (size_t)(obase + o2) * RED + r0);
                    accw[j] = fmaf(wr.x, t0, accw[j]);
                    accw[j] = fmaf(wr.y, t1, accw[j]);
                    accw[j] = fmaf(wr.z, t2, accw[j]);
                    accw[j] = fmaf(wr.w, t3, accw[j]);
                }
            }
        }
        #pragma unroll
        for (int j = 0; j < 7; ++j) {
            const int o2 = wv + 8 * j;
            if (o2 < K2) wg[o2][lane] = accw[j];
        }
        __syncthreads();
        #pragma unroll
        for (int cc2 = 0; cc2 < 2; ++cc2) {
            const int cc = wv * 2 + cc2;
            const int cch = gg * GCH + cc;
            const float* fb = feat + ((size_t)bb * CC + cch) * HW;
            float sum = fb[y * WW + lane];
            #pragma unroll
            for (int i = 0; i < 7; ++i) {
                const int yy = y + i - 3;
                if (yy < 0 || yy >= HH) continue;
                const float* frow = fb + yy * WW;
                #pragma unroll
                for (int jx = 0; jx < 7; ++jx) {
                    const int xx = lane + jx - 3;
                    const float fv = (xx >= 0 && xx < WW) ? frow[xx] : 0.f;
                    sum = fmaf(wg[i * 7 + jx][lane], fv, sum);
                }
            }
            out[((size_t)bb * CC + cch) * HW + (size_t)y * WW + lane] = sum;
        }
        __syncthreads();
    }
}

extern "C" void kernel_launch(void* const* d_in, const int* in_sizes, int n_in,
                              void* d_out, int out_size, void* d_ws, size_t ws_size,
                              hipStream_t stream) {
    const float* feat  = (const float*)d_in[0];
    const float* guide = (const float*)d_in[1];
    const float* w1    = (const float*)d_in[2];
    const float* gamma = (const float*)d_in[3];
    const float* beta  = (const float*)d_in[4];
    const float* mean  = (const float*)d_in[5];
    const float* var   = (const float*)d_in[6];
    const float* w2    = (const float*)d_in[7];
    const float* b2    = (const float*)d_in[8];
    float* out = (float*)d_out;

    const size_t t_bytes = (size_t)2 * RED * HW * sizeof(float);  // 2 MB
    if (ws_size >= t_bytes) {
        float* t_ws = (float*)d_ws;
        hipLaunchKernelGGL(k1_t_kernel, dim3(512), dim3(256), 0, stream,
                           guide, w1, gamma, beta, mean, var, t_ws);
        hipLaunchKernelGGL(k2_inv_kernel, dim3(2048), dim3(256), 0, stream,
                           feat, t_ws, w2, b2, out);
    } else {
        hipLaunchKernelGGL(crossinv_fused_kernel, dim3(256), dim3(512), 0, stream,
                           feat, guide, w1, gamma, beta, mean, var, w2, b2, out);
    }
}

// Round 4
// 46.596 us; speedup vs baseline: 3.1155x; 1.1447x over previous
//
#include <hip/hip_runtime.h>

#define CC  256
#define HW  4096
#define HH  64
#define WW  64
#define RED 64
#define K2  49
#define NG  16
#define GCH 16

typedef __attribute__((ext_vector_type(8))) short bf16x8;
typedef __attribute__((ext_vector_type(4))) float f32x4;

__device__ inline unsigned short f2bf(float f) {
    union { float f; unsigned u; } v; v.f = f;
    unsigned r = v.u + 0x7FFF + ((v.u >> 16) & 1);   // round-to-nearest-even
    return (unsigned short)(r >> 16);
}

// ws layout: Tt bf16 [b][y][x][r]  (2*4096*64 = 524288 elts, 1 MB)
//            w2bf bf16 [832][64]   (53248 elts, rows 784.. zero pad) at +1 MB
#define TT_ELTS   524288
#define W2BF_ROWS 832

// ================= Kernel 1: phase A (t -> transposed bf16) + w2->bf16 cvt ==============
// blocks 0..511: (b, y, oq); thread = (o = oq*16 + tid>>4, xq = tid&15), 4 adjacent x.
// blocks 512..537: convert w2 (784x64 f32) -> w2bf (832x64 bf16, zero-padded rows).
__global__ __launch_bounds__(256, 4) void k1_kernel(
    const float* __restrict__ guide,
    const float* __restrict__ w1,
    const float* __restrict__ gamma,
    const float* __restrict__ beta,
    const float* __restrict__ mean,
    const float* __restrict__ var,
    const float* __restrict__ w2,
    unsigned short* __restrict__ tt,
    unsigned short* __restrict__ w2bf)
{
    const int bid = blockIdx.x;
    const int tid = threadIdx.x;

    if (bid >= 512) {                 // ---- w2 -> bf16 (+ zero pad) ----
        const int idx = (bid - 512) * 256 + tid;      // 8-elt chunk id
        if (idx < (W2BF_ROWS * RED) / 8) {
            unsigned short r8[8];
            if (idx * 8 < K2 * NG * RED) {
                const float4 a = *reinterpret_cast<const float4*>(w2 + idx * 8);
                const float4 b = *reinterpret_cast<const float4*>(w2 + idx * 8 + 4);
                r8[0] = f2bf(a.x); r8[1] = f2bf(a.y); r8[2] = f2bf(a.z); r8[3] = f2bf(a.w);
                r8[4] = f2bf(b.x); r8[5] = f2bf(b.y); r8[6] = f2bf(b.z); r8[7] = f2bf(b.w);
            } else {
                #pragma unroll
                for (int i = 0; i < 8; ++i) r8[i] = 0;
            }
            *reinterpret_cast<uint4*>(w2bf + idx * 8) = *reinterpret_cast<const uint4*>(r8);
        }
        return;
    }

    const int bb  = bid >> 8;
    const int y   = (bid >> 2) & 63;
    const int oq  = bid & 3;
    const int o   = oq * 16 + (tid >> 4);
    const int xq  = tid & 15;
    const int x0  = xq * 4;

    const float* gb   = guide + (size_t)bb * CC * HW + (size_t)y * WW + x0;
    const float* wrow = w1 + (size_t)o * CC;

    float a0 = 0.f, a1 = 0.f, a2 = 0.f, a3 = 0.f;
    #pragma unroll 4
    for (int c0 = 0; c0 < CC; c0 += 4) {
        const float4 w4 = *reinterpret_cast<const float4*>(wrow + c0);
        const float4 g0 = *reinterpret_cast<const float4*>(gb + (size_t)(c0 + 0) * HW);
        const float4 g1 = *reinterpret_cast<const float4*>(gb + (size_t)(c0 + 1) * HW);
        const float4 g2 = *reinterpret_cast<const float4*>(gb + (size_t)(c0 + 2) * HW);
        const float4 g3 = *reinterpret_cast<const float4*>(gb + (size_t)(c0 + 3) * HW);
        a0 = fmaf(w4.x, g0.x, a0); a1 = fmaf(w4.x, g0.y, a1);
        a2 = fmaf(w4.x, g0.z, a2); a3 = fmaf(w4.x, g0.w, a3);
        a0 = fmaf(w4.y, g1.x, a0); a1 = fmaf(w4.y, g1.y, a1);
        a2 = fmaf(w4.y, g1.z, a2); a3 = fmaf(w4.y, g1.w, a3);
        a0 = fmaf(w4.z, g2.x, a0); a1 = fmaf(w4.z, g2.y, a1);
        a2 = fmaf(w4.z, g2.z, a2); a3 = fmaf(w4.z, g2.w, a3);
        a0 = fmaf(w4.w, g3.x, a0); a1 = fmaf(w4.w, g3.y, a1);
        a2 = fmaf(w4.w, g3.z, a2); a3 = fmaf(w4.w, g3.w, a3);
    }

    const float sc = gamma[o] * rsqrtf(var[o] + 1e-5f);
    const float sh = beta[o] - mean[o] * sc;
    float r0 = fmaf(a0, sc, sh), r1 = fmaf(a1, sc, sh);
    float r2 = fmaf(a2, sc, sh), r3 = fmaf(a3, sc, sh);
    r0 = r0 > 0.f ? r0 : 0.f;  r1 = r1 > 0.f ? r1 : 0.f;
    r2 = r2 > 0.f ? r2 : 0.f;  r3 = r3 > 0.f ? r3 : 0.f;

    // transposed bf16 write: Tt[(bb*4096 + y*64 + x)*64 + o]
    const size_t base = ((size_t)bb * HW + (size_t)y * WW + x0) * RED + o;
    tt[base          ] = f2bf(r0);
    tt[base + RED    ] = f2bf(r1);
    tt[base + RED * 2] = f2bf(r2);
    tt[base + RED * 3] = f2bf(r3);
}

// ================= Kernel 2: phase B via MFMA + phase C involution =================
// grid: (b, y, g) = 2048 blocks, 256 thr (4 waves). wave wv = N-tile (16 px).
__global__ __launch_bounds__(256, 4) void k2_inv_kernel(
    const float* __restrict__ feat,
    const unsigned short* __restrict__ tt,
    const unsigned short* __restrict__ w2bf,
    const float* __restrict__ b2,
    float* __restrict__ out)
{
    __shared__ float wg[K2][WW];    // 12.25 KB

    const int bid = blockIdx.x;
    const int bb  = bid >> 10;
    const int y   = (bid >> 4) & 63;
    const int g   = bid & 15;
    const int tid  = threadIdx.x;
    const int lane = tid & 63;
    const int wv   = __builtin_amdgcn_readfirstlane(tid >> 6);  // N-tile id
    const int obase = g * K2;

    const int lm = lane & 15;   // col within tile
    const int lg = lane >> 4;   // k-group

    // ---- Phase B: wg[0..48][x] = w2 @ t + b2 via 8x mfma_f32_16x16x32_bf16 ----
    // A = w2 rows (M=o2), direct from global (k-contiguous).
    // B = Tt (K=r contiguous per x), direct from global.
    f32x4 acc[4] = {f32x4{0,0,0,0}, f32x4{0,0,0,0}, f32x4{0,0,0,0}, f32x4{0,0,0,0}};
    const size_t ttbase = ((size_t)bb * HW + (size_t)y * WW + wv * 16 + lm) * RED + lg * 8;
    #pragma unroll
    for (int ks = 0; ks < 2; ++ks) {
        const bf16x8 bfr = *reinterpret_cast<const bf16x8*>(tt + ttbase + ks * 32);
        #pragma unroll
        for (int mt = 0; mt < 4; ++mt) {
            const bf16x8 afr = *reinterpret_cast<const bf16x8*>(
                w2bf + (size_t)(obase + mt * 16 + lm) * RED + ks * 32 + lg * 8);
            acc[mt] = __builtin_amdgcn_mfma_f32_16x16x32_bf16(afr, bfr, acc[mt], 0, 0, 0);
        }
    }
    // C/D layout (verified): col = lane&15, row = (lane>>4)*4 + reg
    #pragma unroll
    for (int mt = 0; mt < 4; ++mt) {
        #pragma unroll
        for (int rr = 0; rr < 4; ++rr) {
            const int o2 = mt * 16 + lg * 4 + rr;
            if (o2 < K2) wg[o2][wv * 16 + lm] = acc[mt][rr] + b2[obase + o2];
        }
    }
    __syncthreads();

    // ---- Phase C: thread = (channel cl, x-quad xq); 4 adjacent px per thread ----
    const int cl = tid >> 4;
    const int xq = tid & 15;
    const int x0 = xq * 4;
    const int c  = g * GCH + cl;
    const float* fb = feat + ((size_t)bb * CC + c) * HW;

    const float4 res = *reinterpret_cast<const float4*>(fb + (size_t)y * WW + x0);
    float s0 = res.x, s1 = res.y, s2 = res.z, s3 = res.w;   // residual

    #pragma unroll
    for (int i = 0; i < 7; ++i) {
        const int yy = y + i - 3;
        if (yy < 0 || yy >= HH) continue;          // block-uniform branch
        const float* frow = fb + (size_t)yy * WW;

        float4 Lw = make_float4(0.f, 0.f, 0.f, 0.f);
        float4 Rw = make_float4(0.f, 0.f, 0.f, 0.f);
        const float4 Mw = *reinterpret_cast<const float4*>(frow + x0);
        if (xq > 0)  Lw = *reinterpret_cast<const float4*>(frow + x0 - 4);
        if (xq < 15) Rw = *reinterpret_cast<const float4*>(frow + x0 + 4);
        const float buf[12] = {Lw.x, Lw.y, Lw.z, Lw.w,
                               Mw.x, Mw.y, Mw.z, Mw.w,
                               Rw.x, Rw.y, Rw.z, Rw.w};

        #pragma unroll
        for (int jx = 0; jx < 7; ++jx) {
            const float4 w4 = *reinterpret_cast<const float4*>(&wg[i * 7 + jx][x0]);
            s0 = fmaf(w4.x, buf[jx + 1], s0);
            s1 = fmaf(w4.y, buf[jx + 2], s1);
            s2 = fmaf(w4.z, buf[jx + 3], s2);
            s3 = fmaf(w4.w, buf[jx + 4], s3);
        }
    }

    float4 o4; o4.x = s0; o4.y = s1; o4.z = s2; o4.w = s3;
    *reinterpret_cast<float4*>(out + ((size_t)bb * CC + c) * HW + (size_t)y * WW + x0) = o4;
}

// ================= Fallback: fused single kernel (used only if ws too small) =================
__global__ __launch_bounds__(512, 1) void crossinv_fused_kernel(
    const float* __restrict__ feat, const float* __restrict__ guide,
    const float* __restrict__ w1, const float* __restrict__ gamma,
    const float* __restrict__ beta, const float* __restrict__ mean,
    const float* __restrict__ var, const float* __restrict__ w2,
    const float* __restrict__ b2, float* __restrict__ out)
{
    __shared__ float st[RED][WW];
    __shared__ float wg[K2][WW];
    const int bid  = blockIdx.x;
    const int bb   = bid >> 7;
    const int y    = (bid >> 1) & 63;
    const int gsel = bid & 1;
    const int lane = threadIdx.x & 63;
    const int wv   = __builtin_amdgcn_readfirstlane(threadIdx.x >> 6);

    const float* gptr = guide + (size_t)bb * CC * HW + (size_t)y * WW + lane;
    float acc[8];
    #pragma unroll
    for (int j = 0; j < 8; ++j) acc[j] = 0.f;
    for (int c0 = 0; c0 < CC; c0 += 4) {
        const float gv0 = gptr[(c0 + 0) * HW];
        const float gv1 = gptr[(c0 + 1) * HW];
        const float gv2 = gptr[(c0 + 2) * HW];
        const float gv3 = gptr[(c0 + 3) * HW];
        #pragma unroll
        for (int j = 0; j < 8; ++j) {
            const int o = wv + 8 * j;
            const float4 wr = *reinterpret_cast<const float4*>(w1 + o * CC + c0);
            acc[j] = fmaf(wr.x, gv0, acc[j]);
            acc[j] = fmaf(wr.y, gv1, acc[j]);
            acc[j] = fmaf(wr.z, gv2, acc[j]);
            acc[j] = fmaf(wr.w, gv3, acc[j]);
        }
    }
    #pragma unroll
    for (int j = 0; j < 8; ++j) {
        const int o = wv + 8 * j;
        const float sc = gamma[o] * rsqrtf(var[o] + 1e-5f);
        const float sh = beta[o] - mean[o] * sc;
        const float v  = fmaf(acc[j], sc, sh);
        st[o][lane] = v > 0.f ? v : 0.f;
    }
    __syncthreads();
    for (int gi = 0; gi < 8; ++gi) {
        const int gg    = gsel * 8 + gi;
        const int obase = gg * K2;
        float accw[7];
        #pragma unroll
        for (int j = 0; j < 7; ++j) {
            const int o2 = wv + 8 * j;
            accw[j] = (o2 < K2) ? b2[obase + o2] : 0.f;
        }
        for (int r0 = 0; r0 < RED; r0 += 4) {
            const float t0 = st[r0 + 0][lane];
            const float t1 = st[r0 + 1][lane];
            const float t2 = st[r0 + 2][lane];
            const float t3 = st[r0 + 3][lane];
            #pragma unroll
            for (int j = 0; j < 7; ++j) {
                const int o2 = wv + 8 * j;
                if (o2 < K2) {
                    const float4 wr = *reinterpret_cast<const float4*>(
                        w2 + (size_t)(obase + o2) * RED + r0);
                    accw[j] = fmaf(wr.x, t0, accw[j]);
                    accw[j] = fmaf(wr.y, t1, accw[j]);
                    accw[j] = fmaf(wr.z, t2, accw[j]);
                    accw[j] = fmaf(wr.w, t3, accw[j]);
                }
            }
        }
        #pragma unroll
        for (int j = 0; j < 7; ++j) {
            const int o2 = wv + 8 * j;
            if (o2 < K2) wg[o2][lane] = accw[j];
        }
        __syncthreads();
        #pragma unroll
        for (int cc2 = 0; cc2 < 2; ++cc2) {
            const int cc = wv * 2 + cc2;
            const int cch = gg * GCH + cc;
            const float* fb = feat + ((size_t)bb * CC + cch) * HW;
            float sum = fb[y * WW + lane];
            #pragma unroll
            for (int i = 0; i < 7; ++i) {
                const int yy = y + i - 3;
                if (yy < 0 || yy >= HH) continue;
                const float* frow = fb + yy * WW;
                #pragma unroll
                for (int jx = 0; jx < 7; ++jx) {
                    const int xx = lane + jx - 3;
                    const float fv = (xx >= 0 && xx < WW) ? frow[xx] : 0.f;
                    sum = fmaf(wg[i * 7 + jx][lane], fv, sum);
                }
            }
            out[((size_t)bb * CC + cch) * HW + (size_t)y * WW + lane] = sum;
        }
        __syncthreads();
    }
}

extern "C" void kernel_launch(void* const* d_in, const int* in_sizes, int n_in,
                              void* d_out, int out_size, void* d_ws, size_t ws_size,
                              hipStream_t stream) {
    const float* feat  = (const float*)d_in[0];
    const float* guide = (const float*)d_in[1];
    const float* w1    = (const float*)d_in[2];
    const float* gamma = (const float*)d_in[3];
    const float* beta  = (const float*)d_in[4];
    const float* mean  = (const float*)d_in[5];
    const float* var   = (const float*)d_in[6];
    const float* w2    = (const float*)d_in[7];
    const float* b2    = (const float*)d_in[8];
    float* out = (float*)d_out;

    const size_t need = (size_t)TT_ELTS * 2 + (size_t)W2BF_ROWS * RED * 2;  // ~1.1 MB
    if (ws_size >= need) {
        unsigned short* tt   = (unsigned short*)d_ws;
        unsigned short* w2bf = tt + TT_ELTS;
        hipLaunchKernelGGL(k1_kernel, dim3(512 + 26), dim3(256), 0, stream,
                           guide, w1, gamma, beta, mean, var, w2, tt, w2bf);
        hipLaunchKernelGGL(k2_inv_kernel, dim3(2048), dim3(256), 0, stream,
                           feat, tt, w2bf, b2, out);
    } else {
        hipLaunchKernelGGL(crossinv_fused_kernel, dim3(256), dim3(512), 0, stream,
                           feat, guide, w1, gamma, beta, mean, var, w2, b2, out);
    }
}

// Round 5
// 30.188 us; speedup vs baseline: 4.8090x; 1.5435x over previous
//
#include <hip/hip_runtime.h>

#define CC  256
#define HW  4096
#define HH  64
#define WW  64
#define RED 64
#define K2  49
#define NG  16
#define GCH 16

typedef __attribute__((ext_vector_type(8))) short bf16x8;
typedef __attribute__((ext_vector_type(4))) float f32x4;

__device__ inline unsigned short f2bf(float f) {
    union { float f; unsigned u; } v; v.f = f;
    unsigned r = v.u + 0x7FFF + ((v.u >> 16) & 1);   // round-to-nearest-even
    return (unsigned short)(r >> 16);
}

// ws layout: Tt bf16 [b][y][x][r]  (2*4096*64 = 524288 elts, 1 MB)
//            w2bf bf16 [832][64]   (53248 elts, rows 784.. zero pad) at +1 MB
#define TT_ELTS   524288
#define W2BF_ROWS 832

// ================= Kernel 1: phase A via MFMA (+ w2->bf16 tail) =================
// blocks 0..511: (bb, y, nt) each ONE wave (64 thr): t[:, y, nt*16..+15] =
//   relu(BN(w1 @ guide)) via 4m x 8k mfma_f32_16x16x32_bf16, operands
//   converted f32->bf16 in-flight (no staging).
// blocks 512..615: convert w2 (784x64 f32) -> w2bf (832x64 bf16, zero pad).
__global__ __launch_bounds__(64) void k1_kernel(
    const float* __restrict__ guide,
    const float* __restrict__ w1,
    const float* __restrict__ gamma,
    const float* __restrict__ beta,
    const float* __restrict__ mean,
    const float* __restrict__ var,
    const float* __restrict__ w2,
    unsigned short* __restrict__ tt,
    unsigned short* __restrict__ w2bf)
{
    const int bid = blockIdx.x;
    const int tid = threadIdx.x;          // 0..63

    if (bid >= 512) {                     // ---- w2 -> bf16 (+ zero pad) ----
        const int idx = (bid - 512) * 64 + tid;       // 8-elt chunk id
        if (idx < (W2BF_ROWS * RED) / 8) {
            unsigned short r8[8];
            if (idx * 8 < K2 * NG * RED) {
                const float4 a = *reinterpret_cast<const float4*>(w2 + idx * 8);
                const float4 b = *reinterpret_cast<const float4*>(w2 + idx * 8 + 4);
                r8[0] = f2bf(a.x); r8[1] = f2bf(a.y); r8[2] = f2bf(a.z); r8[3] = f2bf(a.w);
                r8[4] = f2bf(b.x); r8[5] = f2bf(b.y); r8[6] = f2bf(b.z); r8[7] = f2bf(b.w);
            } else {
                #pragma unroll
                for (int i = 0; i < 8; ++i) r8[i] = 0;
            }
            *reinterpret_cast<uint4*>(w2bf + idx * 8) = *reinterpret_cast<const uint4*>(r8);
        }
        return;
    }

    const int bb = bid >> 8;
    const int y  = (bid >> 2) & 63;
    const int nt = bid & 3;
    const int lm = tid & 15;              // n-col / m-row within tile
    const int lg = tid >> 4;              // k-group
    const int px = nt * 16 + lm;

    const float* gcol = guide + (size_t)bb * CC * HW + (size_t)y * WW + px;

    f32x4 acc[4] = {f32x4{0,0,0,0}, f32x4{0,0,0,0}, f32x4{0,0,0,0}, f32x4{0,0,0,0}};

    #pragma unroll
    for (int ks = 0; ks < 8; ++ks) {
        const int cbase = ks * 32 + lg * 8;
        // B-frag: guide[cbase..+7][y, px], cvt to bf16
        union { unsigned short u[8]; bf16x8 v; } B;
        #pragma unroll
        for (int j = 0; j < 8; ++j)
            B.u[j] = f2bf(gcol[(size_t)(cbase + j) * HW]);
        #pragma unroll
        for (int mt = 0; mt < 4; ++mt) {
            const float* ar = w1 + (size_t)(mt * 16 + lm) * CC + cbase;
            const float4 a0 = *reinterpret_cast<const float4*>(ar);
            const float4 a1 = *reinterpret_cast<const float4*>(ar + 4);
            union { unsigned short u[8]; bf16x8 v; } A;
            A.u[0] = f2bf(a0.x); A.u[1] = f2bf(a0.y);
            A.u[2] = f2bf(a0.z); A.u[3] = f2bf(a0.w);
            A.u[4] = f2bf(a1.x); A.u[5] = f2bf(a1.y);
            A.u[6] = f2bf(a1.z); A.u[7] = f2bf(a1.w);
            acc[mt] = __builtin_amdgcn_mfma_f32_16x16x32_bf16(A.v, B.v, acc[mt], 0, 0, 0);
        }
    }

    // epilogue: lane holds t[o = mt*16 + lg*4 + rr][px]; BN+ReLU -> bf16 -> Tt[px][o]
    const size_t ttrow = ((size_t)bb * HW + (size_t)y * WW + px) * RED;
    #pragma unroll
    for (int mt = 0; mt < 4; ++mt) {
        union { unsigned short u[4]; uint2 v; } R;
        #pragma unroll
        for (int rr = 0; rr < 4; ++rr) {
            const int o = mt * 16 + lg * 4 + rr;
            const float sc = gamma[o] * rsqrtf(var[o] + 1e-5f);
            const float sh = beta[o] - mean[o] * sc;
            float v = fmaf(acc[mt][rr], sc, sh);
            v = v > 0.f ? v : 0.f;
            R.u[rr] = f2bf(v);
        }
        *reinterpret_cast<uint2*>(tt + ttrow + mt * 16 + lg * 4) = R.v;
    }
}

// ================= Kernel 2: phase B via MFMA + phase C involution ==============
// grid: (bb, y, gp) = 2*64*8 = 1024 blocks, 256 thr (4 waves), 2 groups/block.
// Phase B: wave wv -> group gi=wv>>1, n-half wv&1 (2 n-tiles), 16 MFMA/wave.
// Phase C: thread = (gh=tid>>7, cp=(tid>>4)&7, xq=tid&15): 2 channels x 4 px.
__global__ __launch_bounds__(256, 3) void k2_inv_kernel(
    const float* __restrict__ feat,
    const unsigned short* __restrict__ tt,
    const unsigned short* __restrict__ w2bf,
    const float* __restrict__ b2,
    float* __restrict__ out)
{
    __shared__ float wg[2][K2][WW];       // 24.5 KB

    const int bid = blockIdx.x;
    const int bb  = bid >> 9;
    const int y   = (bid >> 3) & 63;
    const int gp  = bid & 7;
    const int tid  = threadIdx.x;
    const int lane = tid & 63;
    const int wv   = __builtin_amdgcn_readfirstlane(tid >> 6);
    const int lm = lane & 15;
    const int lg = lane >> 4;

    // ---- Phase B ----
    {
        const int gi    = wv >> 1;
        const int g     = gp * 2 + gi;
        const int obase = g * K2;
        f32x4 acc[2][4];
        #pragma unroll
        for (int h = 0; h < 2; ++h)
            #pragma unroll
            for (int mt = 0; mt < 4; ++mt) acc[h][mt] = f32x4{0, 0, 0, 0};

        #pragma unroll
        for (int h = 0; h < 2; ++h) {
            const int nt = (wv & 1) * 2 + h;
            const size_t ttb = ((size_t)bb * HW + (size_t)y * WW + nt * 16 + lm) * RED + lg * 8;
            #pragma unroll
            for (int ks = 0; ks < 2; ++ks) {
                const bf16x8 bfr = *reinterpret_cast<const bf16x8*>(tt + ttb + ks * 32);
                #pragma unroll
                for (int mt = 0; mt < 4; ++mt) {
                    const bf16x8 afr = *reinterpret_cast<const bf16x8*>(
                        w2bf + (size_t)(obase + mt * 16 + lm) * RED + ks * 32 + lg * 8);
                    acc[h][mt] = __builtin_amdgcn_mfma_f32_16x16x32_bf16(afr, bfr, acc[h][mt], 0, 0, 0);
                }
            }
        }
        // C/D layout: col = lane&15, row = lg*4 + rr (+16*mt)
        #pragma unroll
        for (int h = 0; h < 2; ++h)
            #pragma unroll
            for (int mt = 0; mt < 4; ++mt)
                #pragma unroll
                for (int rr = 0; rr < 4; ++rr) {
                    const int o2 = mt * 16 + lg * 4 + rr;
                    if (o2 < K2)
                        wg[gi][o2][(wv & 1) * 32 + h * 16 + lm] = acc[h][mt][rr] + b2[obase + o2];
                }
    }
    __syncthreads();

    // ---- Phase C: 2 channels x 4 px per thread ----
    const int gh = tid >> 7;              // group within block (wave-uniform)
    const int cp = (tid >> 4) & 7;        // channel pair
    const int xq = tid & 15;
    const int x0 = xq * 4;
    const int c0 = (gp * 2 + gh) * GCH + cp * 2;
    const float* fb0 = feat + ((size_t)bb * CC + c0) * HW;
    const float* fb1 = fb0 + HW;

    const float4 rr0 = *reinterpret_cast<const float4*>(fb0 + (size_t)y * WW + x0);
    const float4 rr1 = *reinterpret_cast<const float4*>(fb1 + (size_t)y * WW + x0);
    float s00 = rr0.x, s01 = rr0.y, s02 = rr0.z, s03 = rr0.w;   // residuals
    float s10 = rr1.x, s11 = rr1.y, s12 = rr1.z, s13 = rr1.w;

    #pragma unroll
    for (int i = 0; i < 7; ++i) {
        const int yy = y + i - 3;
        if (yy < 0 || yy >= HH) continue;          // block-uniform branch
        const float* fr0 = fb0 + (size_t)yy * WW;
        const float* fr1 = fb1 + (size_t)yy * WW;

        float4 L0 = make_float4(0.f, 0.f, 0.f, 0.f), L1 = L0;
        float4 R0 = L0, R1 = L0;
        const float4 M0 = *reinterpret_cast<const float4*>(fr0 + x0);
        const float4 M1 = *reinterpret_cast<const float4*>(fr1 + x0);
        if (xq > 0)  { L0 = *reinterpret_cast<const float4*>(fr0 + x0 - 4);
                       L1 = *reinterpret_cast<const float4*>(fr1 + x0 - 4); }
        if (xq < 15) { R0 = *reinterpret_cast<const float4*>(fr0 + x0 + 4);
                       R1 = *reinterpret_cast<const float4*>(fr1 + x0 + 4); }
        const float b0[12] = {L0.x, L0.y, L0.z, L0.w, M0.x, M0.y, M0.z, M0.w,
                              R0.x, R0.y, R0.z, R0.w};
        const float b1[12] = {L1.x, L1.y, L1.z, L1.w, M1.x, M1.y, M1.z, M1.w,
                              R1.x, R1.y, R1.z, R1.w};

        #pragma unroll
        for (int jx = 0; jx < 7; ++jx) {
            const float4 w4 = *reinterpret_cast<const float4*>(&wg[gh][i * 7 + jx][x0]);
            s00 = fmaf(w4.x, b0[jx + 1], s00);
            s01 = fmaf(w4.y, b0[jx + 2], s01);
            s02 = fmaf(w4.z, b0[jx + 3], s02);
            s03 = fmaf(w4.w, b0[jx + 4], s03);
            s10 = fmaf(w4.x, b1[jx + 1], s10);
            s11 = fmaf(w4.y, b1[jx + 2], s11);
            s12 = fmaf(w4.z, b1[jx + 3], s12);
            s13 = fmaf(w4.w, b1[jx + 4], s13);
        }
    }

    float4 o0; o0.x = s00; o0.y = s01; o0.z = s02; o0.w = s03;
    float4 o1; o1.x = s10; o1.y = s11; o1.z = s12; o1.w = s13;
    float* ob = out + ((size_t)bb * CC + c0) * HW + (size_t)y * WW + x0;
    *reinterpret_cast<float4*>(ob)      = o0;
    *reinterpret_cast<float4*>(ob + HW) = o1;
}

// ================= Fallback: fused single kernel (used only if ws too small) =================
__global__ __launch_bounds__(512, 1) void crossinv_fused_kernel(
    const float* __restrict__ feat, const float* __restrict__ guide,
    const float* __restrict__ w1, const float* __restrict__ gamma,
    const float* __restrict__ beta, const float* __restrict__ mean,
    const float* __restrict__ var, const float* __restrict__ w2,
    const float* __restrict__ b2, float* __restrict__ out)
{
    __shared__ float st[RED][WW];
    __shared__ float wg[K2][WW];
    const int bid  = blockIdx.x;
    const int bb   = bid >> 7;
    const int y    = (bid >> 1) & 63;
    const int gsel = bid & 1;
    const int lane = threadIdx.x & 63;
    const int wv   = __builtin_amdgcn_readfirstlane(threadIdx.x >> 6);

    const float* gptr = guide + (size_t)bb * CC * HW + (size_t)y * WW + lane;
    float acc[8];
    #pragma unroll
    for (int j = 0; j < 8; ++j) acc[j] = 0.f;
    for (int c0 = 0; c0 < CC; c0 += 4) {
        const float gv0 = gptr[(c0 + 0) * HW];
        const float gv1 = gptr[(c0 + 1) * HW];
        const float gv2 = gptr[(c0 + 2) * HW];
        const float gv3 = gptr[(c0 + 3) * HW];
        #pragma unroll
        for (int j = 0; j < 8; ++j) {
            const int o = wv + 8 * j;
            const float4 wr = *reinterpret_cast<const float4*>(w1 + o * CC + c0);
            acc[j] = fmaf(wr.x, gv0, acc[j]);
            acc[j] = fmaf(wr.y, gv1, acc[j]);
            acc[j] = fmaf(wr.z, gv2, acc[j]);
            acc[j] = fmaf(wr.w, gv3, acc[j]);
        }
    }
    #pragma unroll
    for (int j = 0; j < 8; ++j) {
        const int o = wv + 8 * j;
        const float sc = gamma[o] * rsqrtf(var[o] + 1e-5f);
        const float sh = beta[o] - mean[o] * sc;
        const float v  = fmaf(acc[j], sc, sh);
        st[o][lane] = v > 0.f ? v : 0.f;
    }
    __syncthreads();
    for (int gi = 0; gi < 8; ++gi) {
        const int gg    = gsel * 8 + gi;
        const int obase = gg * K2;
        float accw[7];
        #pragma unroll
        for (int j = 0; j < 7; ++j) {
            const int o2 = wv + 8 * j;
            accw[j] = (o2 < K2) ? b2[obase + o2] : 0.f;
        }
        for (int r0 = 0; r0 < RED; r0 += 4) {
            const float t0 = st[r0 + 0][lane];
            const float t1 = st[r0 + 1][lane];
            const float t2 = st[r0 + 2][lane];
            const float t3 = st[r0 + 3][lane];
            #pragma unroll
            for (int j = 0; j < 7; ++j) {
                const int o2 = wv + 8 * j;
                if (o2 < K2) {
                    const float4 wr = *reinterpret_cast<const float4*>(
                        w2 + (size_t)(obase + o2) * RED + r0);
                    accw[j] = fmaf(wr.x, t0, accw[j]);
                    accw[j] = fmaf(wr.y, t1, accw[j]);
                    accw[j] = fmaf(wr.z, t2, accw[j]);
                    accw[j] = fmaf(wr.w, t3, accw[j]);
                }
            }
        }
        #pragma unroll
        for (int j = 0; j < 7; ++j) {
            const int o2 = wv + 8 * j;
            if (o2 < K2) wg[o2][lane] = accw[j];
        }
        __syncthreads();
        #pragma unroll
        for (int cc2 = 0; cc2 < 2; ++cc2) {
            const int cc = wv * 2 + cc2;
            const int cch = gg * GCH + cc;
            const float* fb = feat + ((size_t)bb * CC + cch) * HW;
            float sum = fb[y * WW + lane];
            #pragma unroll
            for (int i = 0; i < 7; ++i) {
                const int yy = y + i - 3;
                if (yy < 0 || yy >= HH) continue;
                const float* frow = fb + yy * WW;
                #pragma unroll
                for (int jx = 0; jx < 7; ++jx) {
                    const int xx = lane + jx - 3;
                    const float fv = (xx >= 0 && xx < WW) ? frow[xx] : 0.f;
                    sum = fmaf(wg[i * 7 + jx][lane], fv, sum);
                }
            }
            out[((size_t)bb * CC + cch) * HW + (size_t)y * WW + lane] = sum;
        }
        __syncthreads();
    }
}

extern "C" void kernel_launch(void* const* d_in, const int* in_sizes, int n_in,
                              void* d_out, int out_size, void* d_ws, size_t ws_size,
                              hipStream_t stream) {
    const float* feat  = (const float*)d_in[0];
    const float* guide = (const float*)d_in[1];
    const float* w1    = (const float*)d_in[2];
    const float* gamma = (const float*)d_in[3];
    const float* beta  = (const float*)d_in[4];
    const float* mean  = (const float*)d_in[5];
    const float* var   = (const float*)d_in[6];
    const float* w2    = (const float*)d_in[7];
    const float* b2    = (const float*)d_in[8];
    float* out = (float*)d_out;

    const size_t need = (size_t)TT_ELTS * 2 + (size_t)W2BF_ROWS * RED * 2;  // ~1.1 MB
    if (ws_size >= need) {
        unsigned short* tt   = (unsigned short*)d_ws;
        unsigned short* w2bf = tt + TT_ELTS;
        // 512 MFMA blocks (1 wave each) + 104 w2-convert tail blocks
        hipLaunchKernelGGL(k1_kernel, dim3(512 + 104), dim3(64), 0, stream,
                           guide, w1, gamma, beta, mean, var, w2, tt, w2bf);
        hipLaunchKernelGGL(k2_inv_kernel, dim3(1024), dim3(256), 0, stream,
                           feat, tt, w2bf, b2, out);
    } else {
        hipLaunchKernelGGL(crossinv_fused_kernel, dim3(256), dim3(512), 0, stream,
                           feat, guide, w1, gamma, beta, mean, var, w2, b2, out);
    }
}